// Round 5
// baseline (104.765 us; speedup 1.0000x reference)
//
#include <hip/hip_runtime.h>

#define NATOMS 512
#define N2 (NATOMS*NATOMS)
#define NKPT 32
#define NPOLY 12
#define NSP 4
#define NSMAX 96            // K padded to 3 x 32
#define TJ 128
#define NTHREADS 256

typedef __attribute__((ext_vector_type(8))) short bf16x8;
typedef __attribute__((ext_vector_type(4))) float f32x4;

static __device__ __forceinline__ unsigned f2bf2(float lo, float hi) {
    union { float f; unsigned u; } a, b; a.f = lo; b.f = hi;
    unsigned ra = a.u + 0x7FFFu + ((a.u >> 16) & 1u);   // RNE bf16
    unsigned rb = b.u + 0x7FFFu + ((b.u >> 16) & 1u);
    return (ra >> 16) | (rb & 0xFFFF0000u);
}

// ---- kernel 0: permute shifts near-first / far-last, sentinel-pad to 96 ----
__global__ void prep_shifts(const float* __restrict__ shifts,
                            float4* __restrict__ shp4, int ns)
{
    if (blockIdx.x == 0 && threadIdx.x == 0) {
        int idx = 0;
        for (int pass = 0; pass < 2; ++pass)
            for (int s = 0; s < ns; ++s) {
                float x = shifts[s*3], y = shifts[s*3+1], z = shifts[s*3+2];
                float m = fmaxf(fabsf(x), fmaxf(fabsf(y), fabsf(z)));
                bool far = m > 7.5f;
                if ((pass == 1) == far) shp4[idx++] = make_float4(x, y, z, 0.f);
            }
        for (; idx < NSMAX; ++idx) shp4[idx] = make_float4(1e9f, 1e9f, 1e9f, 0.f);
    }
}

// ---- kernel 1: phase table Ttg[64][96] bf16 (permuted s order) ----
__global__ void phase_tab(const float* __restrict__ kpoints,
                          const float4* __restrict__ shp4,
                          unsigned* __restrict__ Ttg, int ns)
{
    int idx = blockIdx.x * 256 + threadIdx.x;        // 3072 dwords
    if (idx >= 64 * 48) return;
    int row = idx / 48, s2 = idx - row * 48;
    int k = row & 31;
    float kcx = kpoints[k*3]   * 0.2f;
    float kcy = kpoints[k*3+1] * 0.2f;
    float kcz = kpoints[k*3+2] * 0.2f;
    float val[2] = {0.f, 0.f};
    #pragma unroll
    for (int h = 0; h < 2; ++h) {
        int s = 2*s2 + h;
        if (s < ns) {
            float4 sh = shp4[s];
            float d = (kcx*sh.x + kcy*sh.y) + kcz*sh.z;
            float sn, cs;
            sincosf(6.283185307179586f * d, &sn, &cs);
            val[h] = (row >= 32) ? sn : cs;
        }
    }
    Ttg[idx] = f2bf2(val[0], val[1]);
}

// ---- kernel 2: main ----
__global__ __launch_bounds__(NTHREADS, 6)
void dftb5(const float* __restrict__ positions,
           const int* __restrict__ species,
           const float* __restrict__ param,
           const float* __restrict__ onsite,
           const float4* __restrict__ shp4,
           const unsigned short* __restrict__ Ttg,
           float* __restrict__ out)
{
    __shared__ float4 sh4p[NSMAX + NSMAX/8];  // padded: s + s/8 -> 4 g-groups in 4 banks
    __shared__ float cpar4[NPOLY*NSP];        // [q][sj] for this block's si
    __shared__ float4 pjs[TJ];
    __shared__ int sjs[TJ];

    const int tid = threadIdx.x;
    const int bi = blockIdx.x >> 2;           // i row
    const int jt = blockIdx.x & 3;            // j quarter
    const int si = species[bi];

    if (tid < TJ) {
        int j = jt*TJ + tid;
        pjs[tid] = make_float4(positions[j*3], positions[j*3+1], positions[j*3+2], 0.f);
        sjs[tid] = species[j];
    }
    if (tid < NPOLY*NSP) {                    // cpar4[q*4+sj]
        int q = tid >> 2, sj = tid & 3;
        cpar4[tid] = param[(si*NSP + sj)*NPOLY + q];
    }
    for (int s = tid; s < NSMAX; s += NTHREADS)
        sh4p[s + (s >> 3)] = shp4[s];         // sentinels included
    __syncthreads();

    const int lane = tid & 63, w = tid >> 6;
    const int r16 = lane & 15, g = lane >> 4;

    const float pix = positions[bi*3], piy = positions[bi*3+1], piz = positions[bi*3+2];
    const float ons = onsite[si];

    // ---- phase A: A-frags in registers (V in fragment order), 2 mf x 3 kf ----
    bf16x8 A[2][3];
    #pragma unroll
    for (int mf = 0; mf < 2; ++mf) {
        const int jl = w*32 + mf*16 + r16;    // this lane's A-row (local j)
        const float4 pj = pjs[jl];
        const int sj = sjs[jl];
        float c[NPOLY];
        #pragma unroll
        for (int q = 0; q < NPOLY; ++q) c[q] = cpar4[q*4 + sj];

        #pragma unroll
        for (int kf = 0; kf < 3; ++kf) {
            unsigned pk[4];
            #pragma unroll
            for (int e2 = 0; e2 < 4; ++e2) {
                float v[2];
                #pragma unroll
                for (int h = 0; h < 2; ++h) {
                    const int s = kf*32 + g*8 + e2*2 + h;
                    float4 sh = sh4p[s + (s >> 3)];
                    // numpy order: (pj + shift) - pi ; (x^2+y^2)+z^2, no FMA contraction
                    float dx = (pj.x + sh.x) - pix;
                    float dy = (pj.y + sh.y) - piy;
                    float dz = (pj.z + sh.z) - piz;
                    float dr2 = (__fmul_rn(dx,dx) + __fmul_rn(dy,dy)) + __fmul_rn(dz,dz);
                    bool maybe = (dr2 <= 36.001f);          // conservative prefilter
                    float v_ = 0.f;
                    if (__ballot(maybe) != 0ULL) {          // whole-wave skip of far chunks
                        if (maybe) {
                            float dr = sqrtf(dr2);          // correctly-rounded fp32
                            if (dr > 0.1f && dr <= 6.0f) {  // exact gate
                                float x = dr * 1.8897261258369282f;
                                float y = c[NPOLY-1];
                                #pragma unroll
                                for (int q = NPOLY-2; q >= 0; --q) y = fmaf(y, x, c[q]);
                                v_ = y;
                            }
                        }
                    }
                    v[h] = v_;
                }
                pk[e2] = f2bf2(v[0], v[1]);
            }
            union { unsigned u[4]; bf16x8 v; } au;
            au.u[0] = pk[0]; au.u[1] = pk[1]; au.u[2] = pk[2]; au.u[3] = pk[3];
            A[mf][kf] = au.v;
        }
    }

    // ---- phase B: per nf load B-frags (global, L1-hot), MFMA, direct store ----
    const int jbase = jt*TJ + w*32;
    #pragma unroll
    for (int nf = 0; nf < 4; ++nf) {
        const int kcol = nf*16 + r16;         // 0..31 -> Hr plane, 32..63 -> Hi plane
        const unsigned short* tb = Ttg + (size_t)kcol*NSMAX + g*8;
        bf16x8 B0 = *(const bf16x8*)(tb);
        bf16x8 B1 = *(const bf16x8*)(tb + 32);
        bf16x8 B2 = *(const bf16x8*)(tb + 64);
        #pragma unroll
        for (int mf = 0; mf < 2; ++mf) {
            f32x4 acc = {0.f, 0.f, 0.f, 0.f};
            acc = __builtin_amdgcn_mfma_f32_16x16x32_bf16(A[mf][0], B0, acc, 0, 0, 0);
            acc = __builtin_amdgcn_mfma_f32_16x16x32_bf16(A[mf][1], B1, acc, 0, 0, 0);
            acc = __builtin_amdgcn_mfma_f32_16x16x32_bf16(A[mf][2], B2, acc, 0, 0, 0);
            // C/D layout: col(lane&15)=kcol-in-16, row(g*4+reg)=j-in-16
            const int jb = jbase + mf*16 + g*4;
            float4 v; v.x = acc[0]; v.y = acc[1]; v.z = acc[2]; v.w = acc[3];
            if (kcol < 32) {                  // onsite on Hr diagonal
                int d = bi - jb;
                if (d >= 0 && d < 4) ((float*)&v)[d] += ons;
            }
            *(float4*)(out + (size_t)kcol*N2 + (size_t)bi*NATOMS + jb) = v;  // full 64B lines
        }
    }
}

extern "C" void kernel_launch(void* const* d_in, const int* in_sizes, int n_in,
                              void* d_out, int out_size, void* d_ws, size_t ws_size,
                              hipStream_t stream) {
    const float* positions = (const float*)d_in[0];
    const int*   species   = (const int*)d_in[1];
    const float* kpoints   = (const float*)d_in[2];
    const float* param     = (const float*)d_in[3];
    const float* onsite    = (const float*)d_in[4];
    const float* shifts    = (const float*)d_in[5];
    int ns = in_sizes[5] / 3;
    float* out = (float*)d_out;

    float4*   shp4 = (float4*)d_ws;                       // 96*16 = 1536 B
    unsigned* Ttg  = (unsigned*)((char*)d_ws + 2048);     // 64*96*2 = 12 KB

    prep_shifts<<<dim3(1), 64, 0, stream>>>(shifts, shp4, ns);
    phase_tab<<<dim3(12), 256, 0, stream>>>(kpoints, shp4, Ttg, ns);
    dim3 grid(NATOMS * (NATOMS/TJ));                      // 512 * 4 = 2048 blocks
    dftb5<<<grid, NTHREADS, 0, stream>>>(positions, species, param, onsite,
                                         shp4, (const unsigned short*)Ttg, out);
}

// Round 6
// 51.841 us; speedup vs baseline: 2.0209x; 2.0209x over previous
//
#include <hip/hip_runtime.h>

#define NATOMS 512
#define N2 (NATOMS*NATOMS)
#define NKPT 32
#define NPOLY 12
#define NSP 4
#define NSMAX 96            // K padded to 3 x 32 (81 real + sentinels)
#define TJ 128
#define NTHREADS 256
#define VSTR 49             // Vtd row stride in dwords; gcd(49,32)=1 -> conflict-free

typedef __attribute__((ext_vector_type(8))) short bf16x8;
typedef __attribute__((ext_vector_type(4))) float f32x4;

static __device__ __forceinline__ unsigned f2bf2(float lo, float hi) {
    union { float f; unsigned u; } a, b; a.f = lo; b.f = hi;
    unsigned ra = a.u + 0x7FFFu + ((a.u >> 16) & 1u);   // RNE bf16
    unsigned rb = b.u + 0x7FFFu + ((b.u >> 16) & 1u);
    return (ra >> 16) | (rb & 0xFFFF0000u);
}

// ---- kernel 0: permute shifts near-first / big-last, sentinel-pad to 96 ----
__global__ void prep_shifts(const float* __restrict__ shifts,
                            float4* __restrict__ shp4, int ns)
{
    __shared__ unsigned char big[NSMAX];
    int t = threadIdx.x;                  // 128 threads
    bool isbig = false;
    float x = 0.f, y = 0.f, z = 0.f;
    if (t < ns) {
        x = shifts[t*3]; y = shifts[t*3+1]; z = shifts[t*3+2];
        isbig = (fabsf(x) > 7.5f) || (fabsf(y) > 7.5f) || (fabsf(z) > 7.5f);
    }
    if (t < NSMAX) big[t] = (t < ns && isbig) ? 1 : 0;
    __syncthreads();
    if (t < ns) {
        int nnear = 0, rank = 0;
        unsigned char me = isbig ? 1 : 0;
        for (int s = 0; s < ns; ++s) {
            nnear += (big[s] == 0);
            rank  += (s < t) && (big[s] == me);
        }
        int pos = isbig ? (nnear + rank) : rank;
        shp4[pos] = make_float4(x, y, z, 0.f);
    } else if (t < NSMAX) {
        shp4[t] = make_float4(1e9f, 1e9f, 1e9f, 0.f);   // sentinel
    }
}

// ---- kernel 1: phase table Ttg[64][96] bf16 (permuted s order) ----
// rows 0..31: cos(2*pi*(kpt[k]/5).shift[s]); rows 32..63: sin; 0 for s>=ns.
__global__ void phase_tab(const float* __restrict__ kpoints,
                          const float4* __restrict__ shp4,
                          unsigned* __restrict__ Ttg, int ns)
{
    int idx = blockIdx.x * 256 + threadIdx.x;        // 64*48 = 3072 dwords
    if (idx >= 64 * 48) return;
    int row = idx / 48, s2 = idx - row * 48;
    int k = row & 31;
    float kcx = kpoints[k*3]   * 0.2f;
    float kcy = kpoints[k*3+1] * 0.2f;
    float kcz = kpoints[k*3+2] * 0.2f;
    float val[2] = {0.f, 0.f};
    #pragma unroll
    for (int h = 0; h < 2; ++h) {
        int s = 2*s2 + h;
        if (s < ns) {
            float4 sh = shp4[s];
            float d = (kcx*sh.x + kcy*sh.y) + kcz*sh.z;
            float sn, cs;
            sincosf(6.283185307179586f * d, &sn, &cs);
            val[h] = (row >= 32) ? sn : cs;
        }
    }
    Ttg[idx] = f2bf2(val[0], val[1]);
}

// ---- kernel 2: main ----
__global__ __launch_bounds__(NTHREADS, 2)
void dftb6(const float* __restrict__ positions,
           const int* __restrict__ species,
           const float* __restrict__ param,
           const float* __restrict__ onsite,
           const float4* __restrict__ shp4,
           const unsigned short* __restrict__ Ttg,
           float* __restrict__ out)
{
    __shared__ unsigned Vtd[TJ][VSTR];        // V[pair][s] bf16, 2/ dword
    __shared__ float4 sh4s[NSMAX];            // uniform-read -> broadcast
    __shared__ float cpar4[NPOLY*NSP];        // [q][sj] for this block's si
    __shared__ float4 pjs[TJ];
    __shared__ int sjs[TJ];

    const int tid = threadIdx.x;
    const int bi = blockIdx.x >> 2;           // i row
    const int jt = blockIdx.x & 3;            // j quarter
    const int si = species[bi];

    // ---- stage ----
    if (tid < TJ) {
        int j = jt*TJ + tid;
        pjs[tid] = make_float4(positions[j*3], positions[j*3+1], positions[j*3+2], 0.f);
        sjs[tid] = species[j];
    }
    if (tid < NPOLY*NSP) {                    // cpar4[q*4+sj]
        int q = tid >> 2, sj = tid & 3;
        cpar4[tid] = param[(si*NSP + sj)*NPOLY + q];
    }
    if (tid < NSMAX) sh4s[tid] = shp4[tid];
    __syncthreads();

    const float pix = positions[bi*3], piy = positions[bi*3+1], piz = positions[bi*3+2];
    const float ons = onsite[si];

    // ---- phase A: V -> LDS. One pair/thread, wave-uniform s (execz skip) ----
    {
        const int p = tid & (TJ-1);           // pair (local j)
        const int shalf = tid >> 7;           // s-half: 0 -> s 0..47, 1 -> 48..95
        const float4 pj = pjs[p];
        const int sj = sjs[p];
        float c[NPOLY];
        #pragma unroll
        for (int q = 0; q < NPOLY; ++q) c[q] = cpar4[q*4 + sj];

        const int sbase = shalf * 48;
        for (int a = 0; a < 24; ++a) {
            float v2[2];
            #pragma unroll
            for (int h = 0; h < 2; ++h) {
                const int s = sbase + 2*a + h;
                float4 sh = sh4s[s];
                // numpy order: (pj + shift) - pi ; (x^2+y^2)+z^2, no FMA contraction
                float dx = (pj.x + sh.x) - pix;
                float dy = (pj.y + sh.y) - piy;
                float dz = (pj.z + sh.z) - piz;
                float dr2 = (__fmul_rn(dx,dx) + __fmul_rn(dy,dy)) + __fmul_rn(dz,dz);
                float v_ = 0.f;
                if (dr2 <= 36.001f) {         // conservative prefilter (uniform s -> execz)
                    float dr = sqrtf(dr2);    // correctly-rounded fp32
                    if (dr > 0.1f && dr <= 6.0f) {   // exact gate
                        float x = dr * 1.8897261258369282f;
                        float y = c[NPOLY-1];
                        #pragma unroll
                        for (int q = NPOLY-2; q >= 0; --q) y = fmaf(y, x, c[q]);
                        v_ = y;
                    }
                }
                v2[h] = v_;
            }
            Vtd[p][shalf*24 + a] = f2bf2(v2[0], v2[1]);   // b32, stride 49 -> conflict-free
        }
        // dword col 48 (s 96.. pad) never written: VSTR=49 used only for bank spread
        if (shalf == 0) Vtd[p][48] = 0u;      // keep LDS deterministic (not read)
    }
    __syncthreads();

    // ---- phase B: MFMA + direct stores; A re-read from LDS (low pressure) ----
    const int lane = tid & 63, w = tid >> 6;
    const int r16 = lane & 15, g = lane >> 4;

    #pragma unroll
    for (int nf = 0; nf < 4; ++nf) {
        const int kcol = nf*16 + r16;         // 0..31 -> Hr plane, 32..63 -> Hi plane
        const unsigned short* tb = Ttg + (size_t)kcol*NSMAX + g*8;
        bf16x8 B0 = *(const bf16x8*)(tb);
        bf16x8 B1 = *(const bf16x8*)(tb + 32);
        bf16x8 B2 = *(const bf16x8*)(tb + 64);
        #pragma unroll
        for (int mfi = 0; mfi < 2; ++mfi) {
            const int row = w*32 + mfi*16 + r16;          // A row (pair)
            union { unsigned u[4]; bf16x8 v; } a0, a1, a2;
            #pragma unroll
            for (int e = 0; e < 4; ++e) {
                a0.u[e] = Vtd[row][ 0 + g*4 + e];         // kf=0: s 0..31
                a1.u[e] = Vtd[row][16 + g*4 + e];         // kf=1: s 32..63
                a2.u[e] = Vtd[row][32 + g*4 + e];         // kf=2: s 64..95
            }
            f32x4 acc = {0.f, 0.f, 0.f, 0.f};
            acc = __builtin_amdgcn_mfma_f32_16x16x32_bf16(a0.v, B0, acc, 0, 0, 0);
            acc = __builtin_amdgcn_mfma_f32_16x16x32_bf16(a1.v, B1, acc, 0, 0, 0);
            acc = __builtin_amdgcn_mfma_f32_16x16x32_bf16(a2.v, B2, acc, 0, 0, 0);
            // C/D layout: col(lane&15)=kcol-in-16, row(g*4+reg)=pair-in-16
            const int jb = jt*TJ + w*32 + mfi*16 + g*4;
            float4 v; v.x = acc[0]; v.y = acc[1]; v.z = acc[2]; v.w = acc[3];
            if (kcol < 32) {                  // onsite on Hr diagonal
                int d = bi - jb;
                if (d >= 0 && d < 4) ((float*)&v)[d] += ons;
            }
            *(float4*)(out + (size_t)kcol*N2 + (size_t)bi*NATOMS + jb) = v;
        }
    }
}

extern "C" void kernel_launch(void* const* d_in, const int* in_sizes, int n_in,
                              void* d_out, int out_size, void* d_ws, size_t ws_size,
                              hipStream_t stream) {
    const float* positions = (const float*)d_in[0];
    const int*   species   = (const int*)d_in[1];
    const float* kpoints   = (const float*)d_in[2];
    const float* param     = (const float*)d_in[3];
    const float* onsite    = (const float*)d_in[4];
    const float* shifts    = (const float*)d_in[5];
    int ns = in_sizes[5] / 3;
    float* out = (float*)d_out;

    float4*   shp4 = (float4*)d_ws;                       // 96*16 = 1536 B
    unsigned* Ttg  = (unsigned*)((char*)d_ws + 2048);     // 64*96*2 = 12 KB

    prep_shifts<<<dim3(1), 128, 0, stream>>>(shifts, shp4, ns);
    phase_tab<<<dim3(12), 256, 0, stream>>>(kpoints, shp4, Ttg, ns);
    dim3 grid(NATOMS * (NATOMS/TJ));                      // 2048 blocks
    dftb6<<<grid, NTHREADS, 0, stream>>>(positions, species, param, onsite,
                                         shp4, (const unsigned short*)Ttg, out);
}